// Round 3
// baseline (57.545 us; speedup 1.0000x reference)
//
#include <hip/hip_runtime.h>

// LIFSpike forward scan: x [B,N,T] fp32, Vth [N], tau [N] -> out [B,N,T] fp32
// u_t = tau*(u_{t-1} - Vth*o_{t-1}) + x_t ; o_t = (u_t - Vth > 0) ? 1 : 0
//
// R3 strategy: direct per-thread row loads (16x float4, high MLP, no LDS on
// the read side), register scan, and chunked 16 KB LDS staging for fully
// coalesced stores. LDS 64KB->16KB lifts occupancy off the 18% floor.

constexpr int B = 128;
constexpr int N = 4096;
constexpr int T = 64;
constexpr int ROWS = 256;   // sequences per block (= blockDim.x)
constexpr int CH = 16;      // t-chunk staged per store phase
constexpr int NCH = T / CH; // 4 chunks

__global__ __launch_bounds__(256) void lif_spike_kernel(
    const float* __restrict__ x,
    const float* __restrict__ Vth,
    const float* __restrict__ tau,
    float* __restrict__ out)
{
    __shared__ float lds[ROWS * CH];  // 16 KB

    const int tid = threadIdx.x;
    const long long row0 = (long long)blockIdx.x * ROWS;
    const long long grow = row0 + tid;        // this thread's sequence
    const int n = (int)(grow & (N - 1));

    const float vth = fmaxf(Vth[n], 0.0f);              // constrain 'forward'
    const float tc  = fminf(fmaxf(tau[n], 0.0f), 1.0f);

    // Direct strided row load: 16 outstanding dwordx4.
    const float4* __restrict__ xp = reinterpret_cast<const float4*>(x + grow * T);
    float4 xv[T / 4];
    #pragma unroll
    for (int j = 0; j < T / 4; ++j) xv[j] = xp[j];

    const int wbase = tid * CH;
    const int wswz  = (tid >> 1) & 15;   // write-side XOR swizzle (2-way free)

    float u = 0.0f, o = 0.0f;
    const long long tile_word = row0 * T;

    #pragma unroll
    for (int c = 0; c < NCH; ++c) {
        // ---- scan 16 steps, stash spikes into swizzled LDS row ----
        #pragma unroll
        for (int q = 0; q < 4; ++q) {
            const float4 xx = xv[c * 4 + q];
            u = tc * (u - vth * o) + xx.x; o = (u > vth) ? 1.0f : 0.0f;
            lds[wbase + ((q * 4 + 0) ^ wswz)] = o;
            u = tc * (u - vth * o) + xx.y; o = (u > vth) ? 1.0f : 0.0f;
            lds[wbase + ((q * 4 + 1) ^ wswz)] = o;
            u = tc * (u - vth * o) + xx.z; o = (u > vth) ? 1.0f : 0.0f;
            lds[wbase + ((q * 4 + 2) ^ wswz)] = o;
            u = tc * (u - vth * o) + xx.w; o = (u > vth) ? 1.0f : 0.0f;
            lds[wbase + ((q * 4 + 3) ^ wswz)] = o;
        }
        __syncthreads();

        // ---- coalesced store of the [256 rows][16 t] chunk ----
        #pragma unroll
        for (int k2 = 0; k2 < 16; ++k2) {
            const int widx = k2 * 256 + tid;       // word within chunk tile
            const int row  = widx >> 4;
            const int t    = widx & 15;
            const float v  = lds[row * CH + (t ^ ((row >> 1) & 15))];
            out[tile_word + (long long)row * T + c * CH + t] = v;
        }
        __syncthreads();   // protect LDS reuse by next chunk
    }
}

extern "C" void kernel_launch(void* const* d_in, const int* in_sizes, int n_in,
                              void* d_out, int out_size, void* d_ws, size_t ws_size,
                              hipStream_t stream) {
    const float* x   = (const float*)d_in[0];
    const float* Vth = (const float*)d_in[1];
    const float* tau = (const float*)d_in[2];
    float* out       = (float*)d_out;

    const int grid = (B * N) / ROWS;  // 2048 blocks
    lif_spike_kernel<<<grid, 256, 0, stream>>>(x, Vth, tau, out);
}

// Round 4
// 46.139 us; speedup vs baseline: 1.2472x; 1.2472x over previous
//
#include <hip/hip_runtime.h>

// LIFSpike forward scan: x [B,N,T] fp32, Vth [N], tau [N] -> out [B,N,T] fp32
// u_t = tau*(u_{t-1} - Vth*o_{t-1}) + x_t ; o_t = (u_t - Vth > 0) ? 1 : 0
//
// R4 = R2 (full 64KB LDS tile, fully coalesced loads+stores, swizzled
// conflict-free scan) + NONTEMPORAL stores. out (128MB) + x (128MB) exactly
// fill the 256MB L3; write-allocate on out evicts x between graph replays
// (FETCH was 65MB). nt stores keep x L3-resident -> fetch ~0.

constexpr int B = 128;
constexpr int N = 4096;
constexpr int T = 64;
constexpr int ROWS = 256;             // rows (sequences) per block
constexpr int TILE_WORDS = ROWS * T;  // 16384 words = 64 KB

__global__ __launch_bounds__(256) void lif_spike_kernel(
    const float* __restrict__ x,
    const float* __restrict__ Vth,
    const float* __restrict__ tau,
    float* __restrict__ out)
{
    __shared__ float lds[TILE_WORDS];  // 64 KB

    const int tid = threadIdx.x;
    const long long tile_base = (long long)blockIdx.x * TILE_WORDS;

    // ---- Phase A: coalesced global -> LDS (swizzled) ----
    #pragma unroll
    for (int k = 0; k < 64; ++k) {
        const int widx = k * 256 + tid;      // word index within tile
        const int row  = widx >> 6;
        const int t    = widx & 63;
        lds[(row << 6) | (t ^ (row & 31))] = x[tile_base + widx];
    }
    __syncthreads();

    // ---- Phase B: scan own row in LDS (conflict-free via XOR swizzle) ----
    {
        const long long grow = (long long)blockIdx.x * ROWS + tid;  // global row
        const int n = (int)(grow & (N - 1));

        const float vth = fmaxf(Vth[n], 0.0f);             // constrain 'forward'
        const float tc  = fminf(fmaxf(tau[n], 0.0f), 1.0f);

        float u = 0.0f, o = 0.0f;
        const int base = tid << 6;
        const int c    = tid & 31;
        #pragma unroll
        for (int t = 0; t < 64; ++t) {
            const int idx = base | (t ^ c);
            const float xt = lds[idx];
            u = tc * (u - vth * o) + xt;
            o = (u > vth) ? 1.0f : 0.0f;
            lds[idx] = o;   // in-place: same thread owns the row
        }
    }
    __syncthreads();

    // ---- Phase C: coalesced LDS -> global, NONTEMPORAL (don't thrash L3) ----
    #pragma unroll
    for (int k = 0; k < 64; ++k) {
        const int widx = k * 256 + tid;
        const int row  = widx >> 6;
        const int t    = widx & 63;
        const float v  = lds[(row << 6) | (t ^ (row & 31))];
        __builtin_nontemporal_store(v, &out[tile_base + widx]);
    }
}

extern "C" void kernel_launch(void* const* d_in, const int* in_sizes, int n_in,
                              void* d_out, int out_size, void* d_ws, size_t ws_size,
                              hipStream_t stream) {
    const float* x   = (const float*)d_in[0];
    const float* Vth = (const float*)d_in[1];
    const float* tau = (const float*)d_in[2];
    float* out       = (float*)d_out;

    const int grid = (B * N) / ROWS;  // 2048 blocks
    lif_spike_kernel<<<grid, 256, 0, stream>>>(x, Vth, tau, out);
}

// Round 5
// 43.873 us; speedup vs baseline: 1.3116x; 1.0516x over previous
//
#include <hip/hip_runtime.h>

// LIFSpike forward scan: x [B,N,T] fp32, Vth [N], tau [N] -> out [B,N,T] fp32
// u_t = tau*(u_{t-1} - Vth*o_{t-1}) + x_t ; o_t = (u_t - Vth > 0) ? 1 : 0
//
// R5 = R2/R4 structure at single-wave granularity. Each 64-thread block owns
// 64 rows (16 KB LDS). 10 blocks/CU -> loads/scans/stores of different waves
// interleave on the CU, keeping HBM streams fed (R2's 2x64KB blocks left the
// memory pipes idle during compute/barrier phases). Barriers are intra-wave.

constexpr int B = 128;
constexpr int N = 4096;
constexpr int T = 64;
constexpr int ROWS = 64;              // rows (sequences) per block = 1 wave
constexpr int TILE_WORDS = ROWS * T;  // 4096 words = 16 KB

__global__ __launch_bounds__(64) void lif_spike_kernel(
    const float* __restrict__ x,
    const float* __restrict__ Vth,
    const float* __restrict__ tau,
    float* __restrict__ out)
{
    __shared__ float lds[TILE_WORDS];  // 16 KB

    const int tid = threadIdx.x;       // 0..63
    const long long tile_base = (long long)blockIdx.x * TILE_WORDS;

    // ---- Phase A: coalesced global -> LDS (swizzled) ----
    // iteration k: wave reads 64 consecutive words = 256 B/instr coalesced
    #pragma unroll
    for (int k = 0; k < 64; ++k) {
        const int widx = k * 64 + tid;       // word index within tile
        const int row  = k;                  // widx >> 6 == k
        const int t    = tid;                // widx & 63
        lds[(row << 6) | (t ^ (row & 31))] = x[tile_base + widx];
    }
    __syncthreads();

    // ---- Phase B: scan own row in LDS (conflict-free via XOR swizzle) ----
    {
        const long long grow = (long long)blockIdx.x * ROWS + tid;  // global row
        const int n = (int)(grow & (N - 1));

        const float vth = fmaxf(Vth[n], 0.0f);             // constrain 'forward'
        const float tc  = fminf(fmaxf(tau[n], 0.0f), 1.0f);

        float u = 0.0f, o = 0.0f;
        const int base = tid << 6;
        const int c    = tid & 31;
        #pragma unroll
        for (int t = 0; t < 64; ++t) {
            const int idx = base | (t ^ c);
            const float xt = lds[idx];
            u = tc * (u - vth * o) + xt;
            o = (u > vth) ? 1.0f : 0.0f;
            lds[idx] = o;   // in-place: same thread owns the row
        }
    }
    __syncthreads();

    // ---- Phase C: coalesced LDS -> global, nontemporal ----
    #pragma unroll
    for (int k = 0; k < 64; ++k) {
        const int widx = k * 64 + tid;
        const int row  = k;
        const int t    = tid;
        const float v  = lds[(row << 6) | (t ^ (row & 31))];
        __builtin_nontemporal_store(v, &out[tile_base + widx]);
    }
}

extern "C" void kernel_launch(void* const* d_in, const int* in_sizes, int n_in,
                              void* d_out, int out_size, void* d_ws, size_t ws_size,
                              hipStream_t stream) {
    const float* x   = (const float*)d_in[0];
    const float* Vth = (const float*)d_in[1];
    const float* tau = (const float*)d_in[2];
    float* out       = (float*)d_out;

    const int grid = (B * N) / ROWS;  // 8192 blocks
    lif_spike_kernel<<<grid, 64, 0, stream>>>(x, Vth, tau, out);
}